// Round 1
// baseline (164.793 us; speedup 1.0000x reference)
//
#include <hip/hip_runtime.h>
#include <hip/hip_bf16.h>

// Problem constants (match reference)
#define BATCH 4096
#define NC    1024   // n_concepts (K)
#define NL    512    // n_lemmas   (N)
#define TSTEPS 50
#define GAMMA_C 0.95f
#define KAPPA_C 0.1f
#define FLOOR_C 1e-6f

// ---------------- GEMM: D = c_lex (B x NC) @ W^T (NC x NL), fp32 ------------
// A row-major (B x K), Bw row-major (N x K)  -> "NT" gemm, both K-contiguous.
#define BM 64
#define BN 64
#define BK 32
#define LDA 72   // padded LDS leading stride (words); 72%32=8 -> 2-way (free),
                 // 72*4=288B per k-row keeps float4 reads 16B-aligned.

__global__ __launch_bounds__(256)
void gemm_nt_f32(const float* __restrict__ A, const float* __restrict__ Bw,
                 float* __restrict__ D) {
    __shared__ float As[BK * LDA];
    __shared__ float Bs[BK * LDA];

    const int tid = threadIdx.x;
    const int m0 = blockIdx.x * BM;
    const int n0 = blockIdx.y * BN;

    const int tx = tid & 15;       // 0..15 -> N micro
    const int ty = tid >> 4;       // 0..15 -> M micro
    const int srow = tid >> 3;     // 0..31 staging row
    const int skc  = (tid & 7) * 4;// staging k offset: 0,4,..,28

    float acc[4][4] = {{0.f,0.f,0.f,0.f},{0.f,0.f,0.f,0.f},
                       {0.f,0.f,0.f,0.f},{0.f,0.f,0.f,0.f}};

    for (int kt = 0; kt < NC; kt += BK) {
        // ---- stage A tile (64 x 32) and B tile (64 x 32), k-major in LDS ----
        const float4 av0 = *(const float4*)(A + (size_t)(m0 + srow)      * NC + kt + skc);
        const float4 av1 = *(const float4*)(A + (size_t)(m0 + srow + 32) * NC + kt + skc);
        const float4 bv0 = *(const float4*)(Bw + (size_t)(n0 + srow)      * NC + kt + skc);
        const float4 bv1 = *(const float4*)(Bw + (size_t)(n0 + srow + 32) * NC + kt + skc);

        As[(skc + 0) * LDA + srow]      = av0.x;
        As[(skc + 1) * LDA + srow]      = av0.y;
        As[(skc + 2) * LDA + srow]      = av0.z;
        As[(skc + 3) * LDA + srow]      = av0.w;
        As[(skc + 0) * LDA + srow + 32] = av1.x;
        As[(skc + 1) * LDA + srow + 32] = av1.y;
        As[(skc + 2) * LDA + srow + 32] = av1.z;
        As[(skc + 3) * LDA + srow + 32] = av1.w;

        Bs[(skc + 0) * LDA + srow]      = bv0.x;
        Bs[(skc + 1) * LDA + srow]      = bv0.y;
        Bs[(skc + 2) * LDA + srow]      = bv0.z;
        Bs[(skc + 3) * LDA + srow]      = bv0.w;
        Bs[(skc + 0) * LDA + srow + 32] = bv1.x;
        Bs[(skc + 1) * LDA + srow + 32] = bv1.y;
        Bs[(skc + 2) * LDA + srow + 32] = bv1.z;
        Bs[(skc + 3) * LDA + srow + 32] = bv1.w;

        __syncthreads();

        #pragma unroll
        for (int k = 0; k < BK; ++k) {
            const float4 a4 = *(const float4*)(As + k * LDA + ty * 4);
            const float4 b4 = *(const float4*)(Bs + k * LDA + tx * 4);
            const float am[4] = {a4.x, a4.y, a4.z, a4.w};
            const float bm[4] = {b4.x, b4.y, b4.z, b4.w};
            #pragma unroll
            for (int i = 0; i < 4; ++i)
                #pragma unroll
                for (int j = 0; j < 4; ++j)
                    acc[i][j] += am[i] * bm[j];
        }
        __syncthreads();
    }

    #pragma unroll
    for (int i = 0; i < 4; ++i) {
        float4 o;
        o.x = acc[i][0]; o.y = acc[i][1]; o.z = acc[i][2]; o.w = acc[i][3];
        *(float4*)(D + (size_t)(m0 + ty * 4 + i) * NL + n0 + tx * 4) = o;
    }
}

// --------------- 50-step recurrence + selection, one wave per row -----------
// Lane l holds a[col] for col = l + 64*j, j=0..7 (512 cols / 64 lanes).
__global__ __launch_bounds__(256)
void iterate_select(const float* __restrict__ D, float* __restrict__ a_out,
                    float* __restrict__ sel_out, float* __restrict__ conf_out) {
    const int wave = threadIdx.x >> 6;         // 0..3
    const int lane = threadIdx.x & 63;
    const int row  = blockIdx.x * 4 + wave;

    const float* __restrict__ drow = D + (size_t)row * NL;

    float d[8], a[8];
    #pragma unroll
    for (int j = 0; j < 8; ++j) {
        d[j] = drow[lane + 64 * j];            // coalesced, 256B per wave per j
        a[j] = 0.f;                             // a0 is zeros
    }

    for (int t = 0; t < TSTEPS; ++t) {
        float local = 0.f;
        #pragma unroll
        for (int j = 0; j < 8; ++j) {
            a[j] = GAMMA_C * a[j] + d[j];
            local += a[j];
        }
        // full-wave butterfly sum (64 lanes)
        float S = local;
        #pragma unroll
        for (int m = 1; m < 64; m <<= 1)
            S += __shfl_xor(S, m, 64);
        #pragma unroll
        for (int j = 0; j < 8; ++j) {
            float v = a[j] - KAPPA_C * (S - a[j]);
            a[j] = v > 0.f ? v : 0.f;
        }
    }

    // ---- epilogue: peak, mean, confidence, first-index argmax ----
    float peak = a[0];
    float ssum = 0.f;
    #pragma unroll
    for (int j = 0; j < 8; ++j) {
        peak = fmaxf(peak, a[j]);
        ssum += a[j];
    }
    #pragma unroll
    for (int m = 1; m < 64; m <<= 1) {
        peak = fmaxf(peak, __shfl_xor(peak, m, 64));
        ssum += __shfl_xor(ssum, m, 64);
    }
    const float mean = ssum * (1.0f / (float)NL);
    const float conf = peak / fmaxf(mean, FLOOR_C);

    int idx = 0x7fffffff;
    #pragma unroll
    for (int j = 0; j < 8; ++j)
        if (a[j] == peak) idx = min(idx, lane + 64 * j);
    #pragma unroll
    for (int m = 1; m < 64; m <<= 1)
        idx = min(idx, __shfl_xor(idx, m, 64));

    float* __restrict__ arow = a_out + (size_t)row * NL;
    #pragma unroll
    for (int j = 0; j < 8; ++j)
        arow[lane + 64 * j] = a[j];

    if (lane == 0) {
        if (sel_out)  sel_out[row]  = (float)idx;
        if (conf_out) conf_out[row] = conf;
    }
}

extern "C" void kernel_launch(void* const* d_in, const int* in_sizes, int n_in,
                              void* d_out, int out_size, void* d_ws, size_t ws_size,
                              hipStream_t stream) {
    const float* c_lex = (const float*)d_in[0];
    const float* W     = (const float*)d_in[1];
    // d_in[2] = a0 (always zeros at launch; recurrence inits a=0 directly)

    float* D = (float*)d_ws;                     // BATCH*NL fp32 = 8 MB scratch

    dim3 g1(BATCH / BM, NL / BN);                // 64 x 8 = 512 blocks
    gemm_nt_f32<<<g1, 256, 0, stream>>>(c_lex, W, D);

    float* a_out = (float*)d_out;
    float* sel   = nullptr;
    float* conf  = nullptr;
    const int base = BATCH * NL;
    if (out_size >= base + 2 * BATCH) {
        // documented layout: (a, selected, confidence)
        sel  = a_out + base;
        conf = a_out + base + BATCH;
    } else if (out_size >= base + BATCH) {
        // int argmax dropped from flat float buffer: (a, confidence)
        conf = a_out + base;
    }
    iterate_select<<<dim3(BATCH / 4), 256, 0, stream>>>(D, a_out, sel, conf);
}

// Round 2
// 146.618 us; speedup vs baseline: 1.1240x; 1.1240x over previous
//
#include <hip/hip_runtime.h>
#include <hip/hip_bf16.h>

// Problem constants (match reference)
#define BATCH 4096
#define NC    1024   // n_concepts (K)
#define NL    512    // n_lemmas   (N)
#define TSTEPS 50
#define GAMMA_C 0.95f
#define KAPPA_C 0.1f
#define FLOOR_C 1e-6f

// ---------------- GEMM: D = c_lex (B x NC) @ W^T, fp32, split-K -------------
// A row-major (B x K), Bw row-major (N x K) -> NT gemm, both K-contiguous.
// 128x128 tile, 8x8 microtile, BK=16, k-major padded LDS.
#define GBM 128
#define GBN 128
#define GBK 16
#define LDP 132   // 128 + 4 words pad; 132*4=528B per k-row, 16B-aligned

__global__ __launch_bounds__(256)
void gemm_f32_splitk(const float* __restrict__ A, const float* __restrict__ Bw,
                     float* __restrict__ Dp, int kPerSplit) {
    __shared__ float As[GBK * LDP];
    __shared__ float Bs[GBK * LDP];

    const int tid = threadIdx.x;
    const int m0 = blockIdx.x * GBM;
    const int n0 = blockIdx.y * GBN;
    const int kb = blockIdx.z * kPerSplit;

    const int tx = tid & 15;        // 0..15 -> N micro (x4)
    const int ty = tid >> 4;        // 0..15 -> M micro (x4)

    // staging: 512 16B-chunks per tile (128 rows x 4 chunks); 2 per thread
    const int r0  = tid >> 2;       // 0..63
    const int kc0 = (tid & 3) * 4;  // 0,4,8,12

    float acc[8][8];
    #pragma unroll
    for (int i = 0; i < 8; ++i)
        #pragma unroll
        for (int j = 0; j < 8; ++j) acc[i][j] = 0.f;

    for (int kt = kb; kt < kb + kPerSplit; kt += GBK) {
        const float4 a0 = *(const float4*)(A  + (size_t)(m0 + r0)      * NC + kt + kc0);
        const float4 a1 = *(const float4*)(A  + (size_t)(m0 + r0 + 64) * NC + kt + kc0);
        const float4 b0 = *(const float4*)(Bw + (size_t)(n0 + r0)      * NC + kt + kc0);
        const float4 b1 = *(const float4*)(Bw + (size_t)(n0 + r0 + 64) * NC + kt + kc0);

        __syncthreads();   // previous compute done before overwrite

        As[(kc0 + 0) * LDP + r0]      = a0.x;
        As[(kc0 + 1) * LDP + r0]      = a0.y;
        As[(kc0 + 2) * LDP + r0]      = a0.z;
        As[(kc0 + 3) * LDP + r0]      = a0.w;
        As[(kc0 + 0) * LDP + r0 + 64] = a1.x;
        As[(kc0 + 1) * LDP + r0 + 64] = a1.y;
        As[(kc0 + 2) * LDP + r0 + 64] = a1.z;
        As[(kc0 + 3) * LDP + r0 + 64] = a1.w;

        Bs[(kc0 + 0) * LDP + r0]      = b0.x;
        Bs[(kc0 + 1) * LDP + r0]      = b0.y;
        Bs[(kc0 + 2) * LDP + r0]      = b0.z;
        Bs[(kc0 + 3) * LDP + r0]      = b0.w;
        Bs[(kc0 + 0) * LDP + r0 + 64] = b1.x;
        Bs[(kc0 + 1) * LDP + r0 + 64] = b1.y;
        Bs[(kc0 + 2) * LDP + r0 + 64] = b1.z;
        Bs[(kc0 + 3) * LDP + r0 + 64] = b1.w;

        __syncthreads();

        #pragma unroll
        for (int k = 0; k < GBK; ++k) {
            const float4 av0 = *(const float4*)(As + k * LDP + ty * 4);
            const float4 av1 = *(const float4*)(As + k * LDP + ty * 4 + 64);
            const float4 bv0 = *(const float4*)(Bs + k * LDP + tx * 4);
            const float4 bv1 = *(const float4*)(Bs + k * LDP + tx * 4 + 64);
            const float am[8] = {av0.x, av0.y, av0.z, av0.w, av1.x, av1.y, av1.z, av1.w};
            const float bm[8] = {bv0.x, bv0.y, bv0.z, bv0.w, bv1.x, bv1.y, bv1.z, bv1.w};
            #pragma unroll
            for (int i = 0; i < 8; ++i)
                #pragma unroll
                for (int j = 0; j < 8; ++j)
                    acc[i][j] = fmaf(am[i], bm[j], acc[i][j]);
        }
    }

    float* Dz = Dp + (size_t)blockIdx.z * BATCH * NL;
    #pragma unroll
    for (int i = 0; i < 8; ++i) {
        const int m = m0 + (i < 4 ? ty * 4 + i : 64 + ty * 4 + (i - 4));
        float4 lo, hi;
        lo.x = acc[i][0]; lo.y = acc[i][1]; lo.z = acc[i][2]; lo.w = acc[i][3];
        hi.x = acc[i][4]; hi.y = acc[i][5]; hi.z = acc[i][6]; hi.w = acc[i][7];
        *(float4*)(Dz + (size_t)m * NL + n0 + tx * 4)      = lo;
        *(float4*)(Dz + (size_t)m * NL + n0 + 64 + tx * 4) = hi;
    }
}

// --------- 50-step recurrence + selection: 16 lanes per row, 32 cols/lane ---
// Only intra-16 shuffles (masks 1,2,4,8) -> cheap ds_swizzle, short chain.
__global__ __launch_bounds__(256)
void iterate_select(const float* __restrict__ Dp, int splitK,
                    float* __restrict__ a_out,
                    float* __restrict__ sel_out, float* __restrict__ conf_out) {
    const int lane = threadIdx.x & 63;
    const int wave = threadIdx.x >> 6;
    const int sub  = lane & 15;     // position within row-group
    const int grp  = lane >> 4;     // which of 4 rows in this wave
    const int row  = blockIdx.x * 16 + wave * 4 + grp;

    // lane owns cols [sub*32, sub*32+32)
    float d[32];
    {
        const float4* dr = (const float4*)(Dp + (size_t)row * NL + sub * 32);
        #pragma unroll
        for (int p = 0; p < 8; ++p) {
            const float4 v = dr[p];
            d[4 * p + 0] = v.x; d[4 * p + 1] = v.y; d[4 * p + 2] = v.z; d[4 * p + 3] = v.w;
        }
        for (int s = 1; s < splitK; ++s) {
            const float4* dr2 = (const float4*)(Dp + (size_t)s * BATCH * NL
                                                + (size_t)row * NL + sub * 32);
            #pragma unroll
            for (int p = 0; p < 8; ++p) {
                const float4 v = dr2[p];
                d[4 * p + 0] += v.x; d[4 * p + 1] += v.y;
                d[4 * p + 2] += v.z; d[4 * p + 3] += v.w;
            }
        }
    }

    float a[32];
    #pragma unroll
    for (int j = 0; j < 32; ++j) a[j] = 0.f;

    const float K1 = 1.0f + KAPPA_C;

    for (int t = 0; t < TSTEPS; ++t) {
        #pragma unroll
        for (int j = 0; j < 32; ++j) a[j] = fmaf(GAMMA_C, a[j], d[j]);

        // explicit pairwise tree sum of 32 values
        float t16[16], t8[8], t4[4], t2[2];
        #pragma unroll
        for (int j = 0; j < 16; ++j) t16[j] = a[j] + a[j + 16];
        #pragma unroll
        for (int j = 0; j < 8; ++j)  t8[j] = t16[j] + t16[j + 8];
        #pragma unroll
        for (int j = 0; j < 4; ++j)  t4[j] = t8[j] + t8[j + 4];
        t2[0] = t4[0] + t4[2]; t2[1] = t4[1] + t4[3];
        float S = t2[0] + t2[1];

        // intra-16 butterfly (masks < 16 never cross the row group)
        S += __shfl_xor(S, 1, 64);
        S += __shfl_xor(S, 2, 64);
        S += __shfl_xor(S, 4, 64);
        S += __shfl_xor(S, 8, 64);

        const float h = -KAPPA_C * S;
        #pragma unroll
        for (int j = 0; j < 32; ++j) {
            const float v = fmaf(K1, a[j], h);
            a[j] = v > 0.f ? v : 0.f;
        }
    }

    // ---- epilogue: peak, sum, confidence, first-index argmax ----
    float m16[16], m8[8], m4[4];
    float s16[16], s8[8], s4[4];
    #pragma unroll
    for (int j = 0; j < 16; ++j) { m16[j] = fmaxf(a[j], a[j + 16]); s16[j] = a[j] + a[j + 16]; }
    #pragma unroll
    for (int j = 0; j < 8; ++j)  { m8[j] = fmaxf(m16[j], m16[j + 8]); s8[j] = s16[j] + s16[j + 8]; }
    #pragma unroll
    for (int j = 0; j < 4; ++j)  { m4[j] = fmaxf(m8[j], m8[j + 4]); s4[j] = s8[j] + s8[j + 4]; }
    float peak = fmaxf(fmaxf(m4[0], m4[1]), fmaxf(m4[2], m4[3]));
    float ssum = (s4[0] + s4[1]) + (s4[2] + s4[3]);

    peak = fmaxf(peak, __shfl_xor(peak, 1, 64));
    peak = fmaxf(peak, __shfl_xor(peak, 2, 64));
    peak = fmaxf(peak, __shfl_xor(peak, 4, 64));
    peak = fmaxf(peak, __shfl_xor(peak, 8, 64));
    ssum += __shfl_xor(ssum, 1, 64);
    ssum += __shfl_xor(ssum, 2, 64);
    ssum += __shfl_xor(ssum, 4, 64);
    ssum += __shfl_xor(ssum, 8, 64);

    const float mean = ssum * (1.0f / (float)NL);
    const float conf = peak / fmaxf(mean, FLOOR_C);

    int idx = 0x7fffffff;
    #pragma unroll
    for (int j = 0; j < 32; ++j)
        if (a[j] == peak) idx = min(idx, sub * 32 + j);
    idx = min(idx, __shfl_xor(idx, 1, 64));
    idx = min(idx, __shfl_xor(idx, 2, 64));
    idx = min(idx, __shfl_xor(idx, 4, 64));
    idx = min(idx, __shfl_xor(idx, 8, 64));

    float4* ar = (float4*)(a_out + (size_t)row * NL + sub * 32);
    #pragma unroll
    for (int p = 0; p < 8; ++p) {
        float4 v;
        v.x = a[4 * p + 0]; v.y = a[4 * p + 1]; v.z = a[4 * p + 2]; v.w = a[4 * p + 3];
        ar[p] = v;
    }

    if (sub == 0) {
        if (sel_out)  sel_out[row]  = (float)idx;
        if (conf_out) conf_out[row] = conf;
    }
}

extern "C" void kernel_launch(void* const* d_in, const int* in_sizes, int n_in,
                              void* d_out, int out_size, void* d_ws, size_t ws_size,
                              hipStream_t stream) {
    const float* c_lex = (const float*)d_in[0];
    const float* W     = (const float*)d_in[1];
    // d_in[2] = a0 (zeros at every reset; recurrence inits a=0 directly)

    float* D = (float*)d_ws;
    const size_t partBytes = (size_t)BATCH * NL * sizeof(float);   // 8.39 MB
    int splitK = 1;
    if (ws_size >= 4 * partBytes)      splitK = 4;
    else if (ws_size >= 2 * partBytes) splitK = 2;
    const int kPerSplit = NC / splitK;

    dim3 g1(BATCH / GBM, NL / GBN, splitK);   // 32 x 4 x splitK blocks
    gemm_f32_splitk<<<g1, 256, 0, stream>>>(c_lex, W, D, kPerSplit);

    float* a_out = (float*)d_out;
    float* sel   = nullptr;
    float* conf  = nullptr;
    const int base = BATCH * NL;
    if (out_size >= base + 2 * BATCH) {        // (a, selected, confidence)
        sel  = a_out + base;
        conf = a_out + base + BATCH;
    } else if (out_size >= base + BATCH) {     // (a, confidence)
        conf = a_out + base;
    }
    iterate_select<<<dim3(BATCH / 16), 256, 0, stream>>>(D, splitK, a_out, sel, conf);
}

// Round 3
// 140.155 us; speedup vs baseline: 1.1758x; 1.0461x over previous
//
#include <hip/hip_runtime.h>
#include <hip/hip_bf16.h>

// Problem constants (match reference)
#define BATCH 4096
#define NC    1024   // n_concepts (K)
#define NL    512    // n_lemmas   (N)
#define TSTEPS 50
#define GAMMA_C 0.95f
#define KAPPA_C 0.1f
#define FLOOR_C 1e-6f

// ---------------- GEMM: D = c_lex (B x NC) @ W^T, fp32, split-K -------------
// A row-major (B x K), Bw row-major (N x K) -> NT gemm, both K-contiguous.
// 128x128 tile, 8x8 microtile, BK=16, k-major padded LDS.
// 2-stage software pipeline: global->regs prefetch overlaps compute.
#define GBM 128
#define GBN 128
#define GBK 16
#define LDP 132   // 128 + 4 words pad; 16B-aligned rows, write pattern 2-way max

__global__ __launch_bounds__(256)
void gemm_f32_splitk(const float* __restrict__ A, const float* __restrict__ Bw,
                     float* __restrict__ Dp, int kPerSplit) {
    __shared__ float As[GBK * LDP];
    __shared__ float Bs[GBK * LDP];

    const int tid = threadIdx.x;
    const int m0 = blockIdx.x * GBM;
    const int n0 = blockIdx.y * GBN;
    const int kb = blockIdx.z * kPerSplit;
    const int kend = kb + kPerSplit;

    const int tx = tid & 15;        // 0..15 -> N micro (x4 + x4)
    const int ty = tid >> 4;        // 0..15 -> M micro (x4 + x4)

    // staging: each thread owns one float4 k-chunk of 2 A-rows and 2 B-rows
    const int r0  = tid >> 2;       // 0..63
    const int kc0 = (tid & 3) * 4;  // 0,4,8,12

    const float* pA0 = A  + (size_t)(m0 + r0) * NC + kc0;
    const float* pA1 = pA0 + (size_t)64 * NC;
    const float* pB0 = Bw + (size_t)(n0 + r0) * NC + kc0;
    const float* pB1 = pB0 + (size_t)64 * NC;

    float* wA = As + kc0 * LDP + r0;   // writes at [j*LDP], [j*LDP+64]
    float* wB = Bs + kc0 * LDP + r0;

    float acc[8][8];
    #pragma unroll
    for (int i = 0; i < 8; ++i)
        #pragma unroll
        for (int j = 0; j < 8; ++j) acc[i][j] = 0.f;

    // prologue: load first tile into regs
    float4 a0 = *(const float4*)(pA0 + kb);
    float4 a1 = *(const float4*)(pA1 + kb);
    float4 b0 = *(const float4*)(pB0 + kb);
    float4 b1 = *(const float4*)(pB1 + kb);

    for (int kt = kb; kt < kend; kt += GBK) {
        // ---- commit staged regs to LDS (waits vmcnt here, after prior compute)
        wA[0 * LDP]      = a0.x;  wA[1 * LDP]      = a0.y;
        wA[2 * LDP]      = a0.z;  wA[3 * LDP]      = a0.w;
        wA[0 * LDP + 64] = a1.x;  wA[1 * LDP + 64] = a1.y;
        wA[2 * LDP + 64] = a1.z;  wA[3 * LDP + 64] = a1.w;
        wB[0 * LDP]      = b0.x;  wB[1 * LDP]      = b0.y;
        wB[2 * LDP]      = b0.z;  wB[3 * LDP]      = b0.w;
        wB[0 * LDP + 64] = b1.x;  wB[1 * LDP + 64] = b1.y;
        wB[2 * LDP + 64] = b1.z;  wB[3 * LDP + 64] = b1.w;
        __syncthreads();

        // ---- issue next tile's global loads (latency hidden by compute below)
        const int ktn = (kt + GBK < kend) ? kt + GBK : kb;  // harmless reload on last
        a0 = *(const float4*)(pA0 + ktn);
        a1 = *(const float4*)(pA1 + ktn);
        b0 = *(const float4*)(pB0 + ktn);
        b1 = *(const float4*)(pB1 + ktn);

        // ---- compute 16 k-steps from LDS
        #pragma unroll
        for (int k = 0; k < GBK; ++k) {
            const float4 av0 = *(const float4*)(As + k * LDP + ty * 4);
            const float4 av1 = *(const float4*)(As + k * LDP + ty * 4 + 64);
            const float4 bv0 = *(const float4*)(Bs + k * LDP + tx * 4);
            const float4 bv1 = *(const float4*)(Bs + k * LDP + tx * 4 + 64);
            const float am[8] = {av0.x, av0.y, av0.z, av0.w, av1.x, av1.y, av1.z, av1.w};
            const float bm[8] = {bv0.x, bv0.y, bv0.z, bv0.w, bv1.x, bv1.y, bv1.z, bv1.w};
            #pragma unroll
            for (int i = 0; i < 8; ++i)
                #pragma unroll
                for (int j = 0; j < 8; ++j)
                    acc[i][j] = fmaf(am[i], bm[j], acc[i][j]);
        }
        __syncthreads();
    }

    float* Dz = Dp + (size_t)blockIdx.z * BATCH * NL;
    #pragma unroll
    for (int i = 0; i < 8; ++i) {
        const int m = m0 + (i < 4 ? ty * 4 + i : 64 + ty * 4 + (i - 4));
        float4 lo, hi;
        lo.x = acc[i][0]; lo.y = acc[i][1]; lo.z = acc[i][2]; lo.w = acc[i][3];
        hi.x = acc[i][4]; hi.y = acc[i][5]; hi.z = acc[i][6]; hi.w = acc[i][7];
        *(float4*)(Dz + (size_t)m * NL + n0 + tx * 4)      = lo;
        *(float4*)(Dz + (size_t)m * NL + n0 + 64 + tx * 4) = hi;
    }
}

// ------ 50-step recurrence + selection: 32 lanes per row, 16 cols/lane ------
// 2 rows/wave -> 2048 waves (2/SIMD). Shuffle masks 1..16 stay in-row-group.
template<int SK>
__global__ __launch_bounds__(256)
void iterate_select(const float* __restrict__ Dp,
                    float* __restrict__ a_out,
                    float* __restrict__ sel_out, float* __restrict__ conf_out) {
    const int lane = threadIdx.x & 63;
    const int wave = threadIdx.x >> 6;
    const int sub  = lane & 31;     // position within row-group (0..31)
    const int grp  = lane >> 5;     // which of 2 rows in this wave
    const int row  = blockIdx.x * 8 + wave * 2 + grp;

    // lane owns cols [sub*16, sub*16+16)
    float d[16];
    {
        const float4* dr = (const float4*)(Dp + (size_t)row * NL + sub * 16);
        #pragma unroll
        for (int p = 0; p < 4; ++p) {
            const float4 v = dr[p];
            d[4 * p + 0] = v.x; d[4 * p + 1] = v.y; d[4 * p + 2] = v.z; d[4 * p + 3] = v.w;
        }
        #pragma unroll
        for (int s = 1; s < SK; ++s) {
            const float4* dr2 = (const float4*)(Dp + (size_t)s * BATCH * NL
                                                + (size_t)row * NL + sub * 16);
            #pragma unroll
            for (int p = 0; p < 4; ++p) {
                const float4 v = dr2[p];
                d[4 * p + 0] += v.x; d[4 * p + 1] += v.y;
                d[4 * p + 2] += v.z; d[4 * p + 3] += v.w;
            }
        }
    }

    float a[16];
    #pragma unroll
    for (int j = 0; j < 16; ++j) a[j] = 0.f;

    const float K1 = 1.0f + KAPPA_C;

    for (int t = 0; t < TSTEPS; ++t) {
        #pragma unroll
        for (int j = 0; j < 16; ++j) a[j] = fmaf(GAMMA_C, a[j], d[j]);

        // pairwise tree sum of 16 values
        float t8[8], t4[4], t2[2];
        #pragma unroll
        for (int j = 0; j < 8; ++j) t8[j] = a[j] + a[j + 8];
        #pragma unroll
        for (int j = 0; j < 4; ++j) t4[j] = t8[j] + t8[j + 4];
        t2[0] = t4[0] + t4[2]; t2[1] = t4[1] + t4[3];
        float S = t2[0] + t2[1];

        // intra-32 butterfly (masks < 32 never cross the row group)
        S += __shfl_xor(S, 1, 64);
        S += __shfl_xor(S, 2, 64);
        S += __shfl_xor(S, 4, 64);
        S += __shfl_xor(S, 8, 64);
        S += __shfl_xor(S, 16, 64);

        const float h = -KAPPA_C * S;
        #pragma unroll
        for (int j = 0; j < 16; ++j) {
            const float v = fmaf(K1, a[j], h);
            a[j] = v > 0.f ? v : 0.f;
        }
    }

    // ---- epilogue: peak, sum, confidence, first-index argmax ----
    float m8[8], m4[4], s8[8], s4[4];
    #pragma unroll
    for (int j = 0; j < 8; ++j) { m8[j] = fmaxf(a[j], a[j + 8]); s8[j] = a[j] + a[j + 8]; }
    #pragma unroll
    for (int j = 0; j < 4; ++j) { m4[j] = fmaxf(m8[j], m8[j + 4]); s4[j] = s8[j] + s8[j + 4]; }
    float peak = fmaxf(fmaxf(m4[0], m4[1]), fmaxf(m4[2], m4[3]));
    float ssum = (s4[0] + s4[1]) + (s4[2] + s4[3]);

    peak = fmaxf(peak, __shfl_xor(peak, 1, 64));
    peak = fmaxf(peak, __shfl_xor(peak, 2, 64));
    peak = fmaxf(peak, __shfl_xor(peak, 4, 64));
    peak = fmaxf(peak, __shfl_xor(peak, 8, 64));
    peak = fmaxf(peak, __shfl_xor(peak, 16, 64));
    ssum += __shfl_xor(ssum, 1, 64);
    ssum += __shfl_xor(ssum, 2, 64);
    ssum += __shfl_xor(ssum, 4, 64);
    ssum += __shfl_xor(ssum, 8, 64);
    ssum += __shfl_xor(ssum, 16, 64);

    const float mean = ssum * (1.0f / (float)NL);
    const float conf = peak / fmaxf(mean, FLOOR_C);

    int idx = 0x7fffffff;
    #pragma unroll
    for (int j = 0; j < 16; ++j)
        if (a[j] == peak) idx = min(idx, sub * 16 + j);
    idx = min(idx, __shfl_xor(idx, 1, 64));
    idx = min(idx, __shfl_xor(idx, 2, 64));
    idx = min(idx, __shfl_xor(idx, 4, 64));
    idx = min(idx, __shfl_xor(idx, 8, 64));
    idx = min(idx, __shfl_xor(idx, 16, 64));

    float4* ar = (float4*)(a_out + (size_t)row * NL + sub * 16);
    #pragma unroll
    for (int p = 0; p < 4; ++p) {
        float4 v;
        v.x = a[4 * p + 0]; v.y = a[4 * p + 1]; v.z = a[4 * p + 2]; v.w = a[4 * p + 3];
        ar[p] = v;
    }

    if (sub == 0) {
        if (sel_out)  sel_out[row]  = (float)idx;
        if (conf_out) conf_out[row] = conf;
    }
}

extern "C" void kernel_launch(void* const* d_in, const int* in_sizes, int n_in,
                              void* d_out, int out_size, void* d_ws, size_t ws_size,
                              hipStream_t stream) {
    const float* c_lex = (const float*)d_in[0];
    const float* W     = (const float*)d_in[1];
    // d_in[2] = a0 (zeros at every reset; recurrence inits a=0 directly)

    float* D = (float*)d_ws;
    const size_t partBytes = (size_t)BATCH * NL * sizeof(float);   // 8.39 MB
    int splitK = 1;
    if (ws_size >= 4 * partBytes)      splitK = 4;
    else if (ws_size >= 2 * partBytes) splitK = 2;
    const int kPerSplit = NC / splitK;

    dim3 g1(BATCH / GBM, NL / GBN, splitK);   // 32 x 4 x splitK blocks
    gemm_f32_splitk<<<g1, 256, 0, stream>>>(c_lex, W, D, kPerSplit);

    float* a_out = (float*)d_out;
    float* sel   = nullptr;
    float* conf  = nullptr;
    const int base = BATCH * NL;
    if (out_size >= base + 2 * BATCH) {        // (a, selected, confidence)
        sel  = a_out + base;
        conf = a_out + base + BATCH;
    } else if (out_size >= base + BATCH) {     // (a, confidence)
        conf = a_out + base;
    }
    const dim3 g2(BATCH / 8);                  // 512 blocks, 2 rows/wave
    if (splitK == 4)
        iterate_select<4><<<g2, 256, 0, stream>>>(D, a_out, sel, conf);
    else if (splitK == 2)
        iterate_select<2><<<g2, 256, 0, stream>>>(D, a_out, sel, conf);
    else
        iterate_select<1><<<g2, 256, 0, stream>>>(D, a_out, sel, conf);
}

// Round 4
// 114.642 us; speedup vs baseline: 1.4375x; 1.2225x over previous
//
#include <hip/hip_runtime.h>
#include <hip/hip_bf16.h>

// Problem constants (match reference)
#define BATCH 4096
#define NC    1024   // n_concepts (K)
#define NL    512    // n_lemmas   (N)
#define TSTEPS 50
#define GAMMA_C 0.95f
#define KAPPA_C 0.1f
#define FLOOR_C 1e-6f

typedef __attribute__((ext_vector_type(8))) short short8;  // 8 bf16 = 4 VGPRs
typedef __attribute__((ext_vector_type(4))) float f32x4;   // MFMA C/D frag

// ---------------- split fp32 -> bf16 hi + bf16 lo (RNE both) ----------------
__device__ inline void split_bf16(float x, unsigned short& h, unsigned short& l) {
    unsigned u = __float_as_uint(x);
    unsigned rh = u + 0x7FFFu + ((u >> 16) & 1u);
    h = (unsigned short)(rh >> 16);
    float hf = __uint_as_float((unsigned)h << 16);
    float r = x - hf;
    unsigned v = __float_as_uint(r);
    unsigned rl = v + 0x7FFFu + ((v >> 16) & 1u);
    l = (unsigned short)(rl >> 16);
}

// One pass over A (4096x1024) then W (512x1024): float4 in, ushort4 hi + lo out
__global__ __launch_bounds__(256)
void convert_split(const float* __restrict__ A, const float* __restrict__ W,
                   unsigned short* __restrict__ Ahi, unsigned short* __restrict__ Alo,
                   unsigned short* __restrict__ Whi, unsigned short* __restrict__ Wlo) {
    const int chunk = blockIdx.x * 256 + threadIdx.x;     // 0..1179647
    const int fidx  = chunk * 4;
    const float* src;
    unsigned short *dh, *dl;
    if (fidx < BATCH * NC) {
        src = A + fidx; dh = Ahi + fidx; dl = Alo + fidx;
    } else {
        const int o = fidx - BATCH * NC;
        src = W + o; dh = Whi + o; dl = Wlo + o;
    }
    const float4 v = *(const float4*)src;
    ushort4 h4, l4;
    split_bf16(v.x, h4.x, l4.x);
    split_bf16(v.y, h4.y, l4.y);
    split_bf16(v.z, h4.z, l4.z);
    split_bf16(v.w, h4.w, l4.w);
    *(ushort4*)dh = h4;
    *(ushort4*)dl = l4;
}

// ------------- MFMA GEMM: D = Ahi*Whi^T + Ahi*Wlo^T + Alo*Whi^T -------------
// 128x128 tile, splitK=2 (z=0 -> D0 in ws, z=1 -> D1 in d_out's a-region).
// 512 threads = 8 waves (2M x 4N), wave-tile 64x32 via 16x16x32 bf16 MFMA.
#define TM 128
#define TN 128
#define GK 32     // K per LDS stage
#define LDT 40    // ushort stride per LDS row (32 + 8 pad -> 80 B, 2-way only)

__global__ __launch_bounds__(512)
void gemm_bf16x2(const unsigned short* __restrict__ Ahi, const unsigned short* __restrict__ Alo,
                 const unsigned short* __restrict__ Whi, const unsigned short* __restrict__ Wlo,
                 float* __restrict__ D0, float* __restrict__ D1) {
    __shared__ unsigned short AsH[TM * LDT];
    __shared__ unsigned short AsL[TM * LDT];
    __shared__ unsigned short BsH[TN * LDT];
    __shared__ unsigned short BsL[TN * LDT];

    const int tid = threadIdx.x;
    const int m0 = blockIdx.x * TM;
    const int n0 = blockIdx.y * TN;
    const int kb = blockIdx.z * (NC / 2);
    float* __restrict__ D = blockIdx.z ? D1 : D0;

    // staging: thread t owns one 8-ushort chunk of each of the 4 tiles
    const int srow = tid >> 2;         // 0..127
    const int skc  = (tid & 3) * 8;    // 0,8,16,24

    const unsigned short* gAh = Ahi + (size_t)(m0 + srow) * NC + kb + skc;
    const unsigned short* gAl = Alo + (size_t)(m0 + srow) * NC + kb + skc;
    const unsigned short* gBh = Whi + (size_t)(n0 + srow) * NC + kb + skc;
    const unsigned short* gBl = Wlo + (size_t)(n0 + srow) * NC + kb + skc;

    unsigned short* wAh = AsH + srow * LDT + skc;
    unsigned short* wAl = AsL + srow * LDT + skc;
    unsigned short* wBh = BsH + srow * LDT + skc;
    unsigned short* wBl = BsL + srow * LDT + skc;

    // wave layout: 8 waves as 2(M) x 4(N); wave-tile 64x32
    const int lane = tid & 63;
    const int w    = tid >> 6;
    const int mw   = (w >> 2) * 64;
    const int nw   = (w & 3) * 32;
    const int sr   = lane & 15;
    const int quad = lane >> 4;

    const unsigned short* rAh = AsH + (mw + sr) * LDT + quad * 8;
    const unsigned short* rAl = AsL + (mw + sr) * LDT + quad * 8;
    const unsigned short* rBh = BsH + (nw + sr) * LDT + quad * 8;
    const unsigned short* rBl = BsL + (nw + sr) * LDT + quad * 8;

    f32x4 acc[4][2];
    #pragma unroll
    for (int i = 0; i < 4; ++i)
        #pragma unroll
        for (int j = 0; j < 2; ++j)
            acc[i][j] = (f32x4){0.f, 0.f, 0.f, 0.f};

    // prologue: first stage into regs
    short8 pAh = *(const short8*)gAh;
    short8 pAl = *(const short8*)gAl;
    short8 pBh = *(const short8*)gBh;
    short8 pBl = *(const short8*)gBl;

    for (int kt = 0; kt < NC / 2; kt += GK) {
        *(short8*)wAh = pAh;
        *(short8*)wAl = pAl;
        *(short8*)wBh = pBh;
        *(short8*)wBl = pBl;
        __syncthreads();

        const int kn = (kt + GK < NC / 2) ? kt + GK : 0;  // harmless wrap reload
        pAh = *(const short8*)(gAh + kn);
        pAl = *(const short8*)(gAl + kn);
        pBh = *(const short8*)(gBh + kn);
        pBl = *(const short8*)(gBl + kn);

        short8 afh[4], afl[4], bfh[2], bfl[2];
        #pragma unroll
        for (int mi = 0; mi < 4; ++mi) {
            afh[mi] = *(const short8*)(rAh + mi * 16 * LDT);
            afl[mi] = *(const short8*)(rAl + mi * 16 * LDT);
        }
        #pragma unroll
        for (int ni = 0; ni < 2; ++ni) {
            bfh[ni] = *(const short8*)(rBh + ni * 16 * LDT);
            bfl[ni] = *(const short8*)(rBl + ni * 16 * LDT);
        }

        #pragma unroll
        for (int mi = 0; mi < 4; ++mi) {
            #pragma unroll
            for (int ni = 0; ni < 2; ++ni) {
                acc[mi][ni] = __builtin_amdgcn_mfma_f32_16x16x32_bf16(
                    afh[mi], bfh[ni], acc[mi][ni], 0, 0, 0);
                acc[mi][ni] = __builtin_amdgcn_mfma_f32_16x16x32_bf16(
                    afh[mi], bfl[ni], acc[mi][ni], 0, 0, 0);
                acc[mi][ni] = __builtin_amdgcn_mfma_f32_16x16x32_bf16(
                    afl[mi], bfh[ni], acc[mi][ni], 0, 0, 0);
            }
        }
        __syncthreads();
    }

    // epilogue: C/D layout col = lane&15, row = quad*4 + reg  [m89/m91]
    #pragma unroll
    for (int mi = 0; mi < 4; ++mi) {
        #pragma unroll
        for (int ni = 0; ni < 2; ++ni) {
            const int col = n0 + nw + ni * 16 + sr;
            #pragma unroll
            for (int r = 0; r < 4; ++r) {
                const int row = m0 + mw + mi * 16 + quad * 4 + r;
                D[(size_t)row * NL + col] = acc[mi][ni][r];
            }
        }
    }
}

// ------ 50-step recurrence + selection: 32 lanes per row, 16 cols/lane ------
// Reads D0 (ws) + D1 (d_out a-region), writes a/sel/conf. a_out aliases D1:
// each element is read and later written by the same thread only -> safe.
__global__ __launch_bounds__(256)
void iterate_select(const float* __restrict__ D0, float* a_out,
                    float* sel_out, float* conf_out) {
    const int lane = threadIdx.x & 63;
    const int wave = threadIdx.x >> 6;
    const int sub  = lane & 31;
    const int grp  = lane >> 5;
    const int row  = blockIdx.x * 8 + wave * 2 + grp;

    float d[16];
    {
        const float4* p0 = (const float4*)(D0    + (size_t)row * NL + sub * 16);
        const float4* p1 = (const float4*)(a_out + (size_t)row * NL + sub * 16);
        #pragma unroll
        for (int p = 0; p < 4; ++p) {
            const float4 v0 = p0[p];
            const float4 v1 = p1[p];
            d[4 * p + 0] = v0.x + v1.x;
            d[4 * p + 1] = v0.y + v1.y;
            d[4 * p + 2] = v0.z + v1.z;
            d[4 * p + 3] = v0.w + v1.w;
        }
    }

    float a[16];
    #pragma unroll
    for (int j = 0; j < 16; ++j) a[j] = 0.f;

    const float K1 = 1.0f + KAPPA_C;

    for (int t = 0; t < TSTEPS; ++t) {
        #pragma unroll
        for (int j = 0; j < 16; ++j) a[j] = fmaf(GAMMA_C, a[j], d[j]);

        float t8[8], t4[4], t2[2];
        #pragma unroll
        for (int j = 0; j < 8; ++j) t8[j] = a[j] + a[j + 8];
        #pragma unroll
        for (int j = 0; j < 4; ++j) t4[j] = t8[j] + t8[j + 4];
        t2[0] = t4[0] + t4[2]; t2[1] = t4[1] + t4[3];
        float S = t2[0] + t2[1];

        S += __shfl_xor(S, 1, 64);
        S += __shfl_xor(S, 2, 64);
        S += __shfl_xor(S, 4, 64);
        S += __shfl_xor(S, 8, 64);
        S += __shfl_xor(S, 16, 64);

        const float h = -KAPPA_C * S;
        #pragma unroll
        for (int j = 0; j < 16; ++j) {
            const float v = fmaf(K1, a[j], h);
            a[j] = v > 0.f ? v : 0.f;
        }
    }

    float m8[8], m4[4], s8[8], s4[4];
    #pragma unroll
    for (int j = 0; j < 8; ++j) { m8[j] = fmaxf(a[j], a[j + 8]); s8[j] = a[j] + a[j + 8]; }
    #pragma unroll
    for (int j = 0; j < 4; ++j) { m4[j] = fmaxf(m8[j], m8[j + 4]); s4[j] = s8[j] + s8[j + 4]; }
    float peak = fmaxf(fmaxf(m4[0], m4[1]), fmaxf(m4[2], m4[3]));
    float ssum = (s4[0] + s4[1]) + (s4[2] + s4[3]);

    peak = fmaxf(peak, __shfl_xor(peak, 1, 64));
    peak = fmaxf(peak, __shfl_xor(peak, 2, 64));
    peak = fmaxf(peak, __shfl_xor(peak, 4, 64));
    peak = fmaxf(peak, __shfl_xor(peak, 8, 64));
    peak = fmaxf(peak, __shfl_xor(peak, 16, 64));
    ssum += __shfl_xor(ssum, 1, 64);
    ssum += __shfl_xor(ssum, 2, 64);
    ssum += __shfl_xor(ssum, 4, 64);
    ssum += __shfl_xor(ssum, 8, 64);
    ssum += __shfl_xor(ssum, 16, 64);

    const float mean = ssum * (1.0f / (float)NL);
    const float conf = peak / fmaxf(mean, FLOOR_C);

    int idx = 0x7fffffff;
    #pragma unroll
    for (int j = 0; j < 16; ++j)
        if (a[j] == peak) idx = min(idx, sub * 16 + j);
    idx = min(idx, __shfl_xor(idx, 1, 64));
    idx = min(idx, __shfl_xor(idx, 2, 64));
    idx = min(idx, __shfl_xor(idx, 4, 64));
    idx = min(idx, __shfl_xor(idx, 8, 64));
    idx = min(idx, __shfl_xor(idx, 16, 64));

    float4* ar = (float4*)(a_out + (size_t)row * NL + sub * 16);
    #pragma unroll
    for (int p = 0; p < 4; ++p) {
        float4 v;
        v.x = a[4 * p + 0]; v.y = a[4 * p + 1]; v.z = a[4 * p + 2]; v.w = a[4 * p + 3];
        ar[p] = v;
    }

    if (sub == 0) {
        if (sel_out)  sel_out[row]  = (float)idx;
        if (conf_out) conf_out[row] = conf;
    }
}

extern "C" void kernel_launch(void* const* d_in, const int* in_sizes, int n_in,
                              void* d_out, int out_size, void* d_ws, size_t ws_size,
                              hipStream_t stream) {
    const float* c_lex = (const float*)d_in[0];
    const float* W     = (const float*)d_in[1];
    // d_in[2] = a0 (zeros at every reset; recurrence inits a=0 directly)

    // workspace layout (27.3 MB total; ws >= 33.5 MB established in r2/r3):
    float* D0 = (float*)d_ws;                                    // 8.39 MB
    unsigned short* Ahi = (unsigned short*)(D0 + BATCH * NL);    // 8.39 MB
    unsigned short* Alo = Ahi + (size_t)BATCH * NC;              // 8.39 MB
    unsigned short* Whi = Alo + (size_t)BATCH * NC;              // 1.05 MB
    unsigned short* Wlo = Whi + (size_t)NL * NC;                 // 1.05 MB

    float* a_out = (float*)d_out;
    float* sel   = nullptr;
    float* conf  = nullptr;
    const int base = BATCH * NL;
    if (out_size >= base + 2 * BATCH) {        // (a, selected, confidence)
        sel  = a_out + base;
        conf = a_out + base + BATCH;
    } else if (out_size >= base + BATCH) {     // (a, confidence)
        conf = a_out + base;
    }

    // 1) split fp32 -> bf16 hi/lo   (4718592 floats / 4 per thread)
    convert_split<<<dim3(4608), 256, 0, stream>>>(c_lex, W, Ahi, Alo, Whi, Wlo);

    // 2) MFMA GEMM, splitK=2: partial 0 -> D0 (ws), partial 1 -> a_out region
    gemm_bf16x2<<<dim3(BATCH / TM, NL / TN, 2), 512, 0, stream>>>(
        Ahi, Alo, Whi, Wlo, D0, a_out);

    // 3) recurrence + selection (sums the two partials during its D load)
    iterate_select<<<dim3(BATCH / 8), 256, 0, stream>>>(D0, a_out, sel, conf);
}